// Round 7
// baseline (116.993 us; speedup 1.0000x reference)
//
#include <hip/hip_runtime.h>

#define BATCH   8
#define VIN     4096
#define CIN     64
#define VOUTN   16384
#define SN      9
#define COUT    32
#define VT      64   // v-positions per dwpw block
#define UPB     32   // u-positions per pool block

typedef unsigned short ushort8 __attribute__((ext_vector_type(8)));

// bf16 <-> f32 (RNE) via HIP bit intrinsics
__device__ __forceinline__ unsigned short f2bf(float f) {
  unsigned u = __float_as_uint(f);
  u += 0x7FFFu + ((u >> 16) & 1u);
  return (unsigned short)(u >> 16);
}
__device__ __forceinline__ float bf2f(unsigned short h) {
  return __uint_as_float((unsigned)h << 16);
}

// Kernel 1: pooled[b,u,c] = sum_{j<3} tv[e_j] * x[b, tc[e_j], c]  -> bf16
// XCD-pinned batch = blockIdx&7. 2 u-rows/thread, all 6 gathers prefetched.
__global__ __launch_bounds__(256) void pool_kernel(
    const float* __restrict__ x, const int* __restrict__ trans_col,
    const float* __restrict__ trans_value, const int* __restrict__ row_map,
    unsigned short* __restrict__ pooled) {
  __shared__ int   scol[UPB * 3];
  __shared__ float sval[UPB * 3];
  int t  = threadIdx.x;
  int b  = blockIdx.x & 7;
  int u0 = (blockIdx.x >> 3) * UPB;
  if (t < UPB * 3) {
    int e   = row_map[u0 * 3 + t];
    scol[t] = trans_col[e];
    sval[t] = trans_value[e];
  }
  __syncthreads();
  int g = t >> 4, l = t & 15;               // 16 lanes x float4 = 256B row
  const float4* xb4 = (const float4*)(x + (size_t)b * VIN * CIN);
  int cA[3], cB[3]; float vA[3], vB[3];
#pragma unroll
  for (int j = 0; j < 3; ++j) {
    cA[j] = scol[g * 3 + j];        vA[j] = sval[g * 3 + j];
    cB[j] = scol[(g + 16) * 3 + j]; vB[j] = sval[(g + 16) * 3 + j];
  }
  float4 pA[3], pB[3];                      // 6 gathers in flight
#pragma unroll
  for (int j = 0; j < 3; ++j) { pA[j] = xb4[cA[j] * 16 + l]; pB[j] = xb4[cB[j] * 16 + l]; }
  float4 a0 = make_float4(0.f, 0.f, 0.f, 0.f), a1 = a0;
#pragma unroll
  for (int j = 0; j < 3; ++j) {
    a0.x += vA[j] * pA[j].x; a0.y += vA[j] * pA[j].y;
    a0.z += vA[j] * pA[j].z; a0.w += vA[j] * pA[j].w;
    a1.x += vB[j] * pB[j].x; a1.y += vB[j] * pB[j].y;
    a1.z += vB[j] * pB[j].z; a1.w += vB[j] * pB[j].w;
  }
  ushort4 h0, h1;
  h0.x = f2bf(a0.x); h0.y = f2bf(a0.y); h0.z = f2bf(a0.z); h0.w = f2bf(a0.w);
  h1.x = f2bf(a1.x); h1.y = f2bf(a1.y); h1.z = f2bf(a1.z); h1.w = f2bf(a1.w);
  ((ushort4*)(pooled + (size_t)((b << 14) + u0 + g) * CIN))[l] = h0;
  ((ushort4*)(pooled + (size_t)((b << 14) + u0 + g + 16) * CIN))[l] = h1;
}

// Kernel 2: 64 v's/block, XCD-pinned batch.
//  Phase A: 8-lane groups, ushort8 gathers, 18 loads prefetched (2 v-chains x 9)
//  Phase B: lane=vl, wave w -> o-block; Wp from LDS (broadcast b128), no s_load storm
__global__ __launch_bounds__(256) void dwpw_kernel(
    const unsigned short* __restrict__ pooled, const int* __restrict__ indices,
    const float* __restrict__ Wd, const float* __restrict__ bd,
    const float* __restrict__ Wp, const float* __restrict__ bp,
    float* __restrict__ out) {
  __shared__ float dw[VT][65];              // phase-B b32 reads: (vl+cc)%32, 2-way free
  __shared__ int   sidx[VT * SN];           // 576 gather indices
  __shared__ float swdT[SN * CIN];          // Wd^T [s][c]
  __shared__ float spT[CIN * 36];           // Wp^T [cc][o], pad 36 (16B-aligned rows)
  int t  = threadIdx.x;
  int b  = blockIdx.x & 7;
  int v0 = (blockIdx.x >> 3) * VT;

  for (int i = t; i < CIN * COUT; i += 256)         // 2048: spT[cc][o] = Wp[o][cc]
    spT[(i & 63) * 36 + (i >> 6)] = Wp[i];
  for (int i = t; i < VT * SN; i += 256) {          // 576
    sidx[i] = indices[v0 * SN + i];
    int c = i / SN, s = i - c * SN;
    swdT[s * CIN + c] = Wd[i];
  }
  __syncthreads();

  // ---- Phase A ----
  int g = t >> 3, l = t & 7, c8 = l * 8;    // 8 lanes x ushort8 = 128B row
  int vl0 = g, vl1 = g + 32;
  const ushort8* pb8 = (const ushort8*)(pooled + (size_t)(b << 14) * CIN);
  int iu0[SN], iu1[SN];
#pragma unroll
  for (int s = 0; s < SN; ++s) { iu0[s] = sidx[vl0 * SN + s]; iu1[s] = sidx[vl1 * SN + s]; }
  ushort8 h0[SN], h1[SN];                   // 18 gathers in flight
#pragma unroll
  for (int s = 0; s < SN; ++s) { h0[s] = pb8[iu0[s] * 8 + l]; h1[s] = pb8[iu1[s] * 8 + l]; }
  float acc0[8], acc1[8];
  float4 bdA = *(const float4*)(bd + c8), bdB = *(const float4*)(bd + c8 + 4);
  acc0[0] = bdA.x; acc0[1] = bdA.y; acc0[2] = bdA.z; acc0[3] = bdA.w;
  acc0[4] = bdB.x; acc0[5] = bdB.y; acc0[6] = bdB.z; acc0[7] = bdB.w;
#pragma unroll
  for (int k = 0; k < 8; ++k) acc1[k] = acc0[k];
#pragma unroll
  for (int s = 0; s < SN; ++s) {
    float4 w0 = *(const float4*)&swdT[s * CIN + c8];
    float4 w1 = *(const float4*)&swdT[s * CIN + c8 + 4];
    acc0[0] += w0.x * bf2f(h0[s][0]); acc0[1] += w0.y * bf2f(h0[s][1]);
    acc0[2] += w0.z * bf2f(h0[s][2]); acc0[3] += w0.w * bf2f(h0[s][3]);
    acc0[4] += w1.x * bf2f(h0[s][4]); acc0[5] += w1.y * bf2f(h0[s][5]);
    acc0[6] += w1.z * bf2f(h0[s][6]); acc0[7] += w1.w * bf2f(h0[s][7]);
    acc1[0] += w0.x * bf2f(h1[s][0]); acc1[1] += w0.y * bf2f(h1[s][1]);
    acc1[2] += w0.z * bf2f(h1[s][2]); acc1[3] += w0.w * bf2f(h1[s][3]);
    acc1[4] += w1.x * bf2f(h1[s][4]); acc1[5] += w1.y * bf2f(h1[s][5]);
    acc1[6] += w1.z * bf2f(h1[s][6]); acc1[7] += w1.w * bf2f(h1[s][7]);
  }
#pragma unroll
  for (int k = 0; k < 8; ++k) { dw[vl0][c8 + k] = acc0[k]; dw[vl1][c8 + k] = acc1[k]; }
  __syncthreads();

  // ---- Phase B ----
  int vl = t & 63;
  int w  = t >> 6;
  int ob = __builtin_amdgcn_readfirstlane(w * 8);
  float accB[8];
#pragma unroll
  for (int oo = 0; oo < 8; ++oo) accB[oo] = bp[ob + oo];
#pragma unroll 8
  for (int cc = 0; cc < CIN; ++cc) {
    float d = dw[vl][cc];
    float4 wa = *(const float4*)&spT[cc * 36 + ob];       // same-addr broadcast
    float4 wb = *(const float4*)&spT[cc * 36 + ob + 4];
    accB[0] += d * wa.x; accB[1] += d * wa.y; accB[2] += d * wa.z; accB[3] += d * wa.w;
    accB[4] += d * wb.x; accB[5] += d * wb.y; accB[6] += d * wb.z; accB[7] += d * wb.w;
  }
  float* op = out + (size_t)((b << 14) + v0 + vl) * COUT + ob;
  float4 r0 = make_float4(fmaxf(accB[0], 0.f), fmaxf(accB[1], 0.f),
                          fmaxf(accB[2], 0.f), fmaxf(accB[3], 0.f));
  float4 r1 = make_float4(fmaxf(accB[4], 0.f), fmaxf(accB[5], 0.f),
                          fmaxf(accB[6], 0.f), fmaxf(accB[7], 0.f));
  *(float4*)op = r0;
  *(float4*)(op + 4) = r1;
}

extern "C" void kernel_launch(void* const* d_in, const int* in_sizes, int n_in,
                              void* d_out, int out_size, void* d_ws, size_t ws_size,
                              hipStream_t stream) {
  const float* x    = (const float*)d_in[0];
  const int*   tc   = (const int*)d_in[2];
  const float* tv   = (const float*)d_in[3];
  const int*   rm   = (const int*)d_in[4];
  const int*   idx  = (const int*)d_in[5];
  const float* Wd   = (const float*)d_in[6];
  const float* bd   = (const float*)d_in[7];
  const float* Wp   = (const float*)d_in[8];
  const float* bp   = (const float*)d_in[9];
  float* out = (float*)d_out;
  unsigned short* pooled = (unsigned short*)d_ws;   // 16 MiB bf16

  pool_kernel<<<BATCH * (VOUTN / UPB), 256, 0, stream>>>(x, tc, tv, rm, pooled);
  dwpw_kernel<<<BATCH * (VOUTN / VT), 256, 0, stream>>>(pooled, idx, Wd, bd, Wp, bp, out);
}